// Round 5
// baseline (298.109 us; speedup 1.0000x reference)
//
#include <hip/hip_runtime.h>
#include <hip/hip_bf16.h>

// DilatedAttention (b=4, n=8192, d=1024, w=2048, r=4):
// 16 independent 512x512 self-attentions at d=1024 over gathered tokens.
// alphas==1 (idx unique), so output = scatter(att) + zero-fill.
//
// R5: deep REGISTER pipelines for K and V operands (depth-7, counted vmcnt,
// fully unrolled => all ring indices static). R2 proved depth-1 reg loads
// stall (6% MfmaUtil, ~600cyc LLC latency vs ~70cyc/iter); R4's LDS-DMA
// ring capped at 3-ahead by LDS size. Depth-7 regs give ~420+ cyc cover
// with no ds_read/DMA hop on the critical path. VGPR budget: 8 waves/CU
// allows 256/wave; rings use ~170.
// LDS now only P (32 KB swizzled) + softmax partials (2 KB).
// Zero-fill moved to gather kernel (2048 blocks, streaming-BW-capable),
// so attn's epilogue only writes the 33.5 MB att scatter and the zero
// stores can't pollute attn's counted vmcnt stream.

typedef __bf16 bf16_t;
typedef __bf16 bf16x8 __attribute__((ext_vector_type(8)));
typedef float floatx4 __attribute__((ext_vector_type(4)));

#define D_MODEL 1024
#define SEG_W   2048
#define RATE    4
#define M_SUB   512
#define NTOK    8192
#define NSEGT   16
#define XG_ELEMS ((long)NSEGT * M_SUB * D_MODEL)

#define MFMA16(a, b, c) __builtin_amdgcn_mfma_f32_16x16x32_bf16((a), (b), (c), 0, 0, 0)

// counted vmcnt wait; n must be compile-time constant after unrolling
__device__ __forceinline__ void vwait(int n) {
    switch (n) {
    case 0:  asm volatile("s_waitcnt vmcnt(0)"  ::: "memory"); break;
    case 4:  asm volatile("s_waitcnt vmcnt(4)"  ::: "memory"); break;
    case 6:  asm volatile("s_waitcnt vmcnt(6)"  ::: "memory"); break;
    case 8:  asm volatile("s_waitcnt vmcnt(8)"  ::: "memory"); break;
    case 12: asm volatile("s_waitcnt vmcnt(12)" ::: "memory"); break;
    case 16: asm volatile("s_waitcnt vmcnt(16)" ::: "memory"); break;
    case 18: asm volatile("s_waitcnt vmcnt(18)" ::: "memory"); break;
    case 20: asm volatile("s_waitcnt vmcnt(20)" ::: "memory"); break;
    case 24: asm volatile("s_waitcnt vmcnt(24)" ::: "memory"); break;
    case 30: asm volatile("s_waitcnt vmcnt(30)" ::: "memory"); break;
    case 36: asm volatile("s_waitcnt vmcnt(36)" ::: "memory"); break;
    }
}

// ---------------------------------------------------------------------------
// K1: gather x[b, s*2048 + off + 4i, :] -> xg bf16 [seg][i][d]
//                                       -> xgT bf16 [seg][d][i]
// + zero-fill of the 3/4 non-idx output rows (moved here from attn epilogue).
// ---------------------------------------------------------------------------
__global__ __launch_bounds__(256) void gather_kernel(
    const float* __restrict__ x, const int* __restrict__ hidp,
    bf16_t* __restrict__ xg, bf16_t* __restrict__ xgT,
    float* __restrict__ out)
{
    const int off = ((hidp[0] % RATE) + RATE) % RATE;
    const int bid = blockIdx.x;
    const int seg = bid >> 7;
    const int rem = bid & 127;
    const int it  = rem >> 4;
    const int dt  = rem & 15;
    const int b   = seg >> 2, s = seg & 3;

    __shared__ ushort tile[64][65];

    const int t  = threadIdx.x;
    const int r  = t >> 2;             // 0..63
    const int cq = (t & 3) << 4;       // 0,16,32,48

    union U8 { bf16x8 v; ushort u[8]; };

    {
        const int  i   = it * 64 + r;
        const long tok = (long)s * SEG_W + off + 4L * i;
        const float* src = x + ((long)b * NTOK + tok) * D_MODEL + dt * 64 + cq;
        float4 f0 = ((const float4*)src)[0];
        float4 f1 = ((const float4*)src)[1];
        float4 f2 = ((const float4*)src)[2];
        float4 f3 = ((const float4*)src)[3];
        U8 lo, hi;
        lo.v[0]=(bf16_t)f0.x; lo.v[1]=(bf16_t)f0.y; lo.v[2]=(bf16_t)f0.z; lo.v[3]=(bf16_t)f0.w;
        lo.v[4]=(bf16_t)f1.x; lo.v[5]=(bf16_t)f1.y; lo.v[6]=(bf16_t)f1.z; lo.v[7]=(bf16_t)f1.w;
        hi.v[0]=(bf16_t)f2.x; hi.v[1]=(bf16_t)f2.y; hi.v[2]=(bf16_t)f2.z; hi.v[3]=(bf16_t)f2.w;
        hi.v[4]=(bf16_t)f3.x; hi.v[5]=(bf16_t)f3.y; hi.v[6]=(bf16_t)f3.z; hi.v[7]=(bf16_t)f3.w;
        bf16_t* dstg = xg + ((long)seg * M_SUB + i) * D_MODEL + dt * 64 + cq;
        *(bf16x8*)(dstg)     = lo.v;
        *(bf16x8*)(dstg + 8) = hi.v;
        #pragma unroll
        for (int j = 0; j < 8; ++j) { tile[r][cq + j] = lo.u[j]; tile[r][cq + 8 + j] = hi.u[j]; }
    }
    __syncthreads();
    {
        const int dc = r;
        const int iq = cq;
        U8 o0, o1;
        #pragma unroll
        for (int j = 0; j < 8; ++j) { o0.u[j] = tile[iq + j][dc]; o1.u[j] = tile[iq + 8 + j][dc]; }
        bf16_t* dstT = xgT + ((long)seg * D_MODEL + dt * 64 + dc) * M_SUB + it * 64 + iq;
        *(bf16x8*)(dstT)     = o0.v;
        *(bf16x8*)(dstT + 8) = o1.v;
    }

    // ---- zero-fill: for this block's 64 i-values and 64-d column slice,
    // zero the 3 non-idx token rows per i (tokens 4i+e', e' != off).
    {
        const floatx4 z = {0.f, 0.f, 0.f, 0.f};
        const int i2 = r;                  // 0..63
        const int c4 = t & 3;              // float4 lane group
        float* obase = out + (long)b * NTOK * D_MODEL + dt * 64;
        #pragma unroll
        for (int e = 0; e < 3; ++e) {
            const int delta = e + (e >= off ? 1 : 0);
            const long tok = (long)s * SEG_W + 4L * (it * 64 + i2) + delta;
            floatx4* dst = (floatx4*)(obase + tok * D_MODEL);
            #pragma unroll
            for (int c = 0; c < 4; ++c)
                __builtin_nontemporal_store(z, dst + c4 + 4 * c);
        }
    }
}

// ---------------------------------------------------------------------------
// K2: fused attention. One block = one (seg, 32-row q-band), 8 waves.
// Waves free-run; K/V operands ride depth-7 register rings from global.
// ---------------------------------------------------------------------------
__global__ __launch_bounds__(512, 2) void attn_kernel(
    const bf16_t* __restrict__ xg, const bf16_t* __restrict__ xgT,
    const int* __restrict__ hidp, float* __restrict__ out)
{
    const int off  = ((hidp[0] % RATE) + RATE) % RATE;
    const int bid0 = blockIdx.x;
    const int sub  = bid0 >> 3;
    const int seg  = (bid0 & 7) * 2 + (sub >> 4);   // seg->XCD locality
    const int band = sub & 15;
    const int b = seg >> 2, s = seg & 3;

    const int tid  = threadIdx.x;
    const int w    = tid >> 6;
    const int lane = tid & 63;
    const int l16  = lane & 15;
    const int quad = lane >> 4;

    __shared__ alignas(16) bf16_t Pl[32 * 512];     // 32 KB, XOR-swizzled
    __shared__ float redmax[8][32];
    __shared__ float redsum[8][32];

    const bf16_t* xs = xg + (long)seg * M_SUB * D_MODEL;

    // Q rows band*32 + {l16, 16+l16} (same for all 8 waves -> L1 hits)
    const bf16_t* qr0 = xs + (long)(band * 32 + l16) * D_MODEL + quad * 8;
    const bf16_t* qr1 = qr0 + 16 * D_MODEL;
    // K rows w*64 + n*16 + l16
    const bf16_t* kb0 = xs + (long)(w * 64 + l16) * D_MODEL + quad * 8;
    const bf16_t* kb1 = kb0 + 16 * D_MODEL;
    const bf16_t* kb2 = kb0 + 32 * D_MODEL;
    const bf16_t* kb3 = kb0 + 48 * D_MODEL;

    // ================= QK: 32 tiles of 32 d, depth-7 register ring ========
    floatx4 accS[2][4];
    #pragma unroll
    for (int m = 0; m < 2; ++m)
        #pragma unroll
        for (int n = 0; n < 4; ++n) accS[m][n] = (floatx4){0.f, 0.f, 0.f, 0.f};

    bf16x8 qf[7][2], kf[7][4];
    auto issueQK = [&](int slot, int tt) {
        const int o = tt * 32;
        qf[slot][0] = *(const bf16x8*)(qr0 + o);
        qf[slot][1] = *(const bf16x8*)(qr1 + o);
        kf[slot][0] = *(const bf16x8*)(kb0 + o);
        kf[slot][1] = *(const bf16x8*)(kb1 + o);
        kf[slot][2] = *(const bf16x8*)(kb2 + o);
        kf[slot][3] = *(const bf16x8*)(kb3 + o);
    };

    #pragma unroll
    for (int p = 0; p < 6; ++p) issueQK(p, p);      // prologue: 6 sets ahead

    #pragma unroll
    for (int t = 0; t < 32; ++t) {
        if (t + 6 < 32) issueQK((t + 6) % 7, t + 6);
        const int ahead = (31 - t) < 6 ? (31 - t) : 6;
        vwait(6 * ahead);                           // set t landed
        const int sl = t % 7;
        #pragma unroll
        for (int n = 0; n < 4; ++n) {
            accS[0][n] = MFMA16(qf[sl][0], kf[sl][n], accS[0][n]);
            accS[1][n] = MFMA16(qf[sl][1], kf[sl][n], accS[1][n]);
        }
    }

    // ================= softmax (f32, cross-wave via LDS) =================
    #pragma unroll
    for (int m = 0; m < 2; ++m)
        #pragma unroll
        for (int n = 0; n < 4; ++n)
            #pragma unroll
            for (int rg = 0; rg < 4; ++rg) accS[m][n][rg] *= 0.03125f;  // 1/sqrt(1024)

    float mx[2][4];
    #pragma unroll
    for (int m = 0; m < 2; ++m)
        #pragma unroll
        for (int rg = 0; rg < 4; ++rg)
            mx[m][rg] = fmaxf(fmaxf(accS[m][0][rg], accS[m][1][rg]),
                              fmaxf(accS[m][2][rg], accS[m][3][rg]));
    #pragma unroll
    for (int d = 1; d < 16; d <<= 1)
        #pragma unroll
        for (int m = 0; m < 2; ++m)
            #pragma unroll
            for (int rg = 0; rg < 4; ++rg)
                mx[m][rg] = fmaxf(mx[m][rg], __shfl_xor(mx[m][rg], d, 64));
    if (l16 == 0) {
        #pragma unroll
        for (int m = 0; m < 2; ++m)
            #pragma unroll
            for (int rg = 0; rg < 4; ++rg)
                redmax[w][m * 16 + quad * 4 + rg] = mx[m][rg];
    }
    __syncthreads();
    float gm[2][4];
    #pragma unroll
    for (int m = 0; m < 2; ++m)
        #pragma unroll
        for (int rg = 0; rg < 4; ++rg) {
            const int row = m * 16 + quad * 4 + rg;
            float g = redmax[0][row];
            #pragma unroll
            for (int ww = 1; ww < 8; ++ww) g = fmaxf(g, redmax[ww][row]);
            gm[m][rg] = g;
        }
    float sm[2][4] = {{0.f,0.f,0.f,0.f},{0.f,0.f,0.f,0.f}};
    #pragma unroll
    for (int m = 0; m < 2; ++m)
        #pragma unroll
        for (int n = 0; n < 4; ++n)
            #pragma unroll
            for (int rg = 0; rg < 4; ++rg) {
                const float e = __expf(accS[m][n][rg] - gm[m][rg]);
                accS[m][n][rg] = e;
                sm[m][rg] += e;
            }
    #pragma unroll
    for (int d = 1; d < 16; d <<= 1)
        #pragma unroll
        for (int m = 0; m < 2; ++m)
            #pragma unroll
            for (int rg = 0; rg < 4; ++rg)
                sm[m][rg] += __shfl_xor(sm[m][rg], d, 64);
    if (l16 == 0) {
        #pragma unroll
        for (int m = 0; m < 2; ++m)
            #pragma unroll
            for (int rg = 0; rg < 4; ++rg)
                redsum[w][m * 16 + quad * 4 + rg] = sm[m][rg];
    }
    __syncthreads();
    float iv[2][4];
    #pragma unroll
    for (int m = 0; m < 2; ++m)
        #pragma unroll
        for (int rg = 0; rg < 4; ++rg) {
            const int row = m * 16 + quad * 4 + rg;
            float tt = redsum[0][row];
            #pragma unroll
            for (int ww = 1; ww < 8; ++ww) tt += redsum[ww][row];
            iv[m][rg] = 1.f / tt;
        }

    // ================= PV setup: V ring prologue + P store ================
    // V rows (xgT d-rows): p*512 + w*64 + n*16 + l16 ; cols = tokens.
    const bf16_t* vb0 = xgT + ((long)seg * D_MODEL + w * 64 + l16) * M_SUB + quad * 8;
    const bf16_t* vb1 = vb0 + 16 * M_SUB;
    const bf16_t* vb2 = vb0 + 32 * M_SUB;
    const bf16_t* vb3 = vb0 + 48 * M_SUB;

    bf16x8 vf[7][4];
    auto issueV = [&](int slot, int t) {
        const int tt = t & 15;                     // token tile within pass
        const long po = (long)(t >> 4) * 512 * M_SUB + tt * 32;
        vf[slot][0] = *(const bf16x8*)(vb0 + po);
        vf[slot][1] = *(const bf16x8*)(vb1 + po);
        vf[slot][2] = *(const bf16x8*)(vb2 + po);
        vf[slot][3] = *(const bf16x8*)(vb3 + po);
    };
    #pragma unroll
    for (int p = 0; p < 6; ++p) issueV(p, p);      // overlap with P store

    // P -> bf16 -> swizzled LDS: chunk c of row r at slot c^(r&7)
    #pragma unroll
    for (int m = 0; m < 2; ++m)
        #pragma unroll
        for (int rg = 0; rg < 4; ++rg) {
            const int row = m * 16 + quad * 4 + rg;
            const float f = iv[m][rg];
            #pragma unroll
            for (int n = 0; n < 4; ++n) {
                const int col = w * 64 + n * 16 + l16;
                const int sw  = (((col >> 3) ^ (row & 7)) << 3) + (col & 7);
                Pl[row * 512 + sw] = (bf16_t)(accS[m][n][rg] * f);
            }
        }
    asm volatile("s_waitcnt lgkmcnt(0)" ::: "memory");  // P visible; V loads live
    __builtin_amdgcn_s_barrier();
    __builtin_amdgcn_sched_barrier(0);

    // ================= PV: 32 linear tiles (2 passes x 16), ring-7 ========
    floatx4 accA[2][4], accB[2][4];
    #pragma unroll
    for (int m = 0; m < 2; ++m)
        #pragma unroll
        for (int n = 0; n < 4; ++n) {
            accA[m][n] = (floatx4){0.f, 0.f, 0.f, 0.f};
            accB[m][n] = (floatx4){0.f, 0.f, 0.f, 0.f};
        }

    bf16x8 pf[2][2];
    auto loadP = [&](int slot, int t) {
        const int tt = t & 15;
        const int ch = (tt * 4 + quad) ^ (l16 & 7);
        pf[slot][0] = *(const bf16x8*)&Pl[(l16) * 512 + ch * 8];
        pf[slot][1] = *(const bf16x8*)&Pl[(16 + l16) * 512 + ch * 8];
    };
    loadP(0, 0);

    #pragma unroll
    for (int t = 0; t < 32; ++t) {
        if (t + 6 < 32) issueV((t + 6) % 7, t + 6);
        const int ahead = (31 - t) < 6 ? (31 - t) : 6;
        vwait(4 * ahead);                          // V set t landed
        if (t + 1 < 32) loadP((t + 1) & 1, t + 1);
        const int sl = t % 7;
        if (t < 16) {
            #pragma unroll
            for (int n = 0; n < 4; ++n) {
                accA[0][n] = MFMA16(pf[t & 1][0], vf[sl][n], accA[0][n]);
                accA[1][n] = MFMA16(pf[t & 1][1], vf[sl][n], accA[1][n]);
            }
        } else {
            #pragma unroll
            for (int n = 0; n < 4; ++n) {
                accB[0][n] = MFMA16(pf[t & 1][0], vf[sl][n], accB[0][n]);
                accB[1][n] = MFMA16(pf[t & 1][1], vf[sl][n], accB[1][n]);
            }
        }
    }

    // ================= epilogue: att scatter only =========================
    float* obase = out + (long)b * NTOK * D_MODEL;
    #pragma unroll
    for (int m = 0; m < 2; ++m)
        #pragma unroll
        for (int rg = 0; rg < 4; ++rg) {
            const long tok = (long)s * SEG_W + off + 4L * (band * 32 + m * 16 + quad * 4 + rg);
            float* orow = obase + tok * D_MODEL;
            #pragma unroll
            for (int n = 0; n < 4; ++n) {
                const int d = w * 64 + n * 16 + l16;
                __builtin_nontemporal_store(accA[m][n][rg], orow + d);
                __builtin_nontemporal_store(accB[m][n][rg], orow + 512 + d);
            }
        }
}

extern "C" void kernel_launch(void* const* d_in, const int* in_sizes, int n_in,
                              void* d_out, int out_size, void* d_ws, size_t ws_size,
                              hipStream_t stream) {
    const float* x   = (const float*)d_in[0];
    const int*   hid = (const int*)d_in[1];
    float*       out = (float*)d_out;
    bf16_t* xg  = (bf16_t*)d_ws;
    bf16_t* xgT = xg + XG_ELEMS;      // ws: 33.6 MB

    gather_kernel<<<dim3(2048), dim3(256), 0, stream>>>(x, hid, xg, xgT, out);
    attn_kernel<<<dim3(256), dim3(512), 0, stream>>>(xg, xgT, hid, out);
}

// Round 6
// 269.704 us; speedup vs baseline: 1.1053x; 1.1053x over previous
//
#include <hip/hip_runtime.h>
#include <hip/hip_bf16.h>

// DilatedAttention (b=4, n=8192, d=1024, w=2048, r=4):
// 16 independent 512x512 self-attentions at d=1024 over gathered tokens.
// alphas==1 (idx unique), so output = scatter(att) + zero-fill.
//
// R6: phase-split for L2 residency. All prior structures converged to
// ~70-85us for attention because per-XCD working set (xg+xgT = 4MB) equals
// L2 size -> reads served by LLC at ~7 TB/s. Split:
//   qk_kernel: reads xg ONLY (2MB/XCD, L2-fits) -> P (global bf16, 8.4MB)
//   pv_kernel: reads xgT ONLY (2MB/XCD, L2-fits) + P -> att scatter
// Both keep R4's proven machinery: free-running waves (per-wave panel
// slices, no per-tile barriers), global_load_lds ring-4 staged 3 ahead,
// counted s_waitcnt vmcnt(12) (sets of 6 vmem), XOR chunk swizzle.
// Zero-fill: full-row (4KB) coalesced stores appended to gather
// (R5's scattered 256-B-chunk version was slow).
// ws: xg 16.78 + xgT 16.78 + P 8.39 = 41.94 MB (same as R0).

typedef __bf16 bf16_t;
typedef __bf16 bf16x8 __attribute__((ext_vector_type(8)));
typedef float floatx4 __attribute__((ext_vector_type(4)));

#define D_MODEL 1024
#define SEG_W   2048
#define RATE    4
#define M_SUB   512
#define NTOK    8192
#define NSEGT   16
#define XG_ELEMS ((long)NSEGT * M_SUB * D_MODEL)
#define P_ELEMS  ((long)NSEGT * M_SUB * M_SUB)

__device__ __forceinline__ void gload16(const bf16_t* g, bf16_t* l) {
    __builtin_amdgcn_global_load_lds(
        (const __attribute__((address_space(1))) void*)g,
        (__attribute__((address_space(3))) void*)l, 16, 0, 0);
}

#define MFMA16(a, b, c) __builtin_amdgcn_mfma_f32_16x16x32_bf16((a), (b), (c), 0, 0, 0)

__device__ __forceinline__ void vwait(int n) {
    switch (n) {
    case 0:  asm volatile("s_waitcnt vmcnt(0)"  ::: "memory"); break;
    case 6:  asm volatile("s_waitcnt vmcnt(6)"  ::: "memory"); break;
    case 12: asm volatile("s_waitcnt vmcnt(12)" ::: "memory"); break;
    }
}

// ---------------------------------------------------------------------------
// K1: gather x[b, s*2048 + off + 4i, :] -> xg bf16 [seg][i][d]
//                                       -> xgT bf16 [seg][d][i]
// + full-row coalesced zero-fill of the 24576 non-idx output rows.
// ---------------------------------------------------------------------------
__global__ __launch_bounds__(256) void gather_kernel(
    const float* __restrict__ x, const int* __restrict__ hidp,
    bf16_t* __restrict__ xg, bf16_t* __restrict__ xgT,
    float* __restrict__ out)
{
    const int off = ((hidp[0] % RATE) + RATE) % RATE;
    const int bid = blockIdx.x;
    const int seg = bid >> 7;
    const int rem = bid & 127;
    const int it  = rem >> 4;
    const int dt  = rem & 15;
    const int b   = seg >> 2, s = seg & 3;

    __shared__ ushort tile[64][65];

    const int t  = threadIdx.x;
    const int r  = t >> 2;
    const int cq = (t & 3) << 4;

    union U8 { bf16x8 v; ushort u[8]; };

    {
        const int  i   = it * 64 + r;
        const long tok = (long)s * SEG_W + off + 4L * i;
        const float* src = x + ((long)b * NTOK + tok) * D_MODEL + dt * 64 + cq;
        float4 f0 = ((const float4*)src)[0];
        float4 f1 = ((const float4*)src)[1];
        float4 f2 = ((const float4*)src)[2];
        float4 f3 = ((const float4*)src)[3];
        U8 lo, hi;
        lo.v[0]=(bf16_t)f0.x; lo.v[1]=(bf16_t)f0.y; lo.v[2]=(bf16_t)f0.z; lo.v[3]=(bf16_t)f0.w;
        lo.v[4]=(bf16_t)f1.x; lo.v[5]=(bf16_t)f1.y; lo.v[6]=(bf16_t)f1.z; lo.v[7]=(bf16_t)f1.w;
        hi.v[0]=(bf16_t)f2.x; hi.v[1]=(bf16_t)f2.y; hi.v[2]=(bf16_t)f2.z; hi.v[3]=(bf16_t)f2.w;
        hi.v[4]=(bf16_t)f3.x; hi.v[5]=(bf16_t)f3.y; hi.v[6]=(bf16_t)f3.z; hi.v[7]=(bf16_t)f3.w;
        bf16_t* dstg = xg + ((long)seg * M_SUB + i) * D_MODEL + dt * 64 + cq;
        *(bf16x8*)(dstg)     = lo.v;
        *(bf16x8*)(dstg + 8) = hi.v;
        #pragma unroll
        for (int j = 0; j < 8; ++j) { tile[r][cq + j] = lo.u[j]; tile[r][cq + 8 + j] = hi.u[j]; }
    }
    __syncthreads();
    {
        const int dc = r;
        const int iq = cq;
        U8 o0, o1;
        #pragma unroll
        for (int j = 0; j < 8; ++j) { o0.u[j] = tile[iq + j][dc]; o1.u[j] = tile[iq + 8 + j][dc]; }
        bf16_t* dstT = xgT + ((long)seg * D_MODEL + dt * 64 + dc) * M_SUB + it * 64 + iq;
        *(bf16x8*)(dstT)     = o0.v;
        *(bf16x8*)(dstT + 8) = o1.v;
    }

    // ---- zero-fill: 12 full 4KB rows per block (24576 rows total),
    // 256 threads x 16B = one row per pass. Independent of gather work.
    {
        const floatx4 z = {0.f, 0.f, 0.f, 0.f};
        #pragma unroll
        for (int k = 0; k < 12; ++k) {
            const int z0 = bid * 12 + k;            // 0..24575
            const int zseg = z0 / 1536;
            const int zz   = z0 - zseg * 1536;
            const int i    = zz / 3;
            const int e    = zz - 3 * i;
            const int delta = e + (e >= off ? 1 : 0);
            const int zb = zseg >> 2, zs = zseg & 3;
            const long tok = (long)zs * SEG_W + 4L * i + delta;
            float* dst = out + ((long)zb * NTOK + tok) * D_MODEL + t * 4;
            __builtin_nontemporal_store(z, (floatx4*)dst);
        }
    }
}

// ---------------------------------------------------------------------------
// K2: QK + softmax -> P (global bf16). One block = (seg, 32-row q-band),
// 8 waves, free-running. Reads xg ONLY (2 MB/XCD working set -> L2).
// K ring: 4 x 32KB panels [512 tok x 32 d], staged 3 ahead; Q reg ring-4.
// Sets of 6 vmem {2 Q + 4 gload_lds}; vmcnt(12) keeps 2 sets in flight.
// ---------------------------------------------------------------------------
__global__ __launch_bounds__(512, 2) void qk_kernel(
    const bf16_t* __restrict__ xg, bf16_t* __restrict__ Pg)
{
    const int bid0 = blockIdx.x;
    const int sub  = bid0 >> 3;
    const int seg  = (bid0 & 7) * 2 + (sub >> 4);   // seg->XCD locality
    const int band = sub & 15;

    const int tid  = threadIdx.x;
    const int w    = tid >> 6;
    const int lane = tid & 63;
    const int l16  = lane & 15;
    const int quad = lane >> 4;

    __shared__ alignas(16) char arena[133120];           // 130 KB
    bf16_t* Kring = (bf16_t*)arena;                      // 4 x 32K
    float (*redmax)[32] = (float(*)[32])(arena + 131072);
    float (*redsum)[32] = (float(*)[32])(arena + 132096);
    bf16_t* Pl = (bf16_t*)arena;                         // reuse after QK

    const bf16_t* xs = xg + (long)seg * M_SUB * D_MODEL;

    const bf16_t* qr0 = xs + (long)(band * 32 + l16) * D_MODEL + quad * 8;
    const bf16_t* qr1 = qr0 + 16 * D_MODEL;
    const bf16_t* ksrc = xs + (long)(w * 64 + (lane >> 2)) * D_MODEL
                            + (((lane & 3) ^ (lane >> 4)) * 8);
    auto stageK = [&](int buf, int t) {
        bf16_t* dst = Kring + buf * 16384 + (w * 64) * 32;
        const bf16_t* src = ksrc + t * 32;
        #pragma unroll
        for (int j = 0; j < 4; ++j)
            gload16(src + j * 16 * D_MODEL, dst + j * 512);
    };

    const int rsw = (l16 >> 2) & 3;   // panel read swizzle key

    floatx4 accS[2][4];
    #pragma unroll
    for (int m = 0; m < 2; ++m)
        #pragma unroll
        for (int n = 0; n < 4; ++n) accS[m][n] = (floatx4){0.f, 0.f, 0.f, 0.f};

    bf16x8 qf[4][2];
    #pragma unroll
    for (int p0 = 0; p0 < 3; ++p0) {          // prologue: sets 0..2
        qf[p0][0] = *(const bf16x8*)(qr0 + p0 * 32);
        qf[p0][1] = *(const bf16x8*)(qr1 + p0 * 32);
        stageK(p0, p0);
    }

    #pragma unroll
    for (int t = 0; t < 32; ++t) {
        if (t <= 29)      vwait(12);          // set t landed; 2 sets in flight
        else if (t == 30) vwait(6);
        else              vwait(0);

        const bf16_t* Kb = Kring + (t & 3) * 16384;
        bf16x8 Bf[4];
        #pragma unroll
        for (int n = 0; n < 4; ++n) {
            const int row = w * 64 + n * 16 + l16;
            Bf[n] = *(const bf16x8*)&Kb[row * 32 + ((quad ^ rsw) * 8)];
        }
        if (t <= 28) {                         // issue set t+3
            qf[(t + 3) & 3][0] = *(const bf16x8*)(qr0 + (t + 3) * 32);
            qf[(t + 3) & 3][1] = *(const bf16x8*)(qr1 + (t + 3) * 32);
            stageK((t + 3) & 3, t + 3);
        }
        #pragma unroll
        for (int n = 0; n < 4; ++n) {
            accS[0][n] = MFMA16(qf[t & 3][0], Bf[n], accS[0][n]);
            accS[1][n] = MFMA16(qf[t & 3][1], Bf[n], accS[1][n]);
        }
    }

    // ---- softmax (f32, cross-wave via LDS)
    #pragma unroll
    for (int m = 0; m < 2; ++m)
        #pragma unroll
        for (int n = 0; n < 4; ++n)
            #pragma unroll
            for (int rg = 0; rg < 4; ++rg) accS[m][n][rg] *= 0.03125f;  // 1/sqrt(1024)

    float mx[2][4];
    #pragma unroll
    for (int m = 0; m < 2; ++m)
        #pragma unroll
        for (int rg = 0; rg < 4; ++rg)
            mx[m][rg] = fmaxf(fmaxf(accS[m][0][rg], accS[m][1][rg]),
                              fmaxf(accS[m][2][rg], accS[m][3][rg]));
    #pragma unroll
    for (int d = 1; d < 16; d <<= 1)
        #pragma unroll
        for (int m = 0; m < 2; ++m)
            #pragma unroll
            for (int rg = 0; rg < 4; ++rg)
                mx[m][rg] = fmaxf(mx[m][rg], __shfl_xor(mx[m][rg], d, 64));
    if (l16 == 0) {
        #pragma unroll
        for (int m = 0; m < 2; ++m)
            #pragma unroll
            for (int rg = 0; rg < 4; ++rg)
                redmax[w][m * 16 + quad * 4 + rg] = mx[m][rg];
    }
    __syncthreads();
    float gm[2][4];
    #pragma unroll
    for (int m = 0; m < 2; ++m)
        #pragma unroll
        for (int rg = 0; rg < 4; ++rg) {
            const int row = m * 16 + quad * 4 + rg;
            float g = redmax[0][row];
            #pragma unroll
            for (int ww = 1; ww < 8; ++ww) g = fmaxf(g, redmax[ww][row]);
            gm[m][rg] = g;
        }
    float sm[2][4] = {{0.f,0.f,0.f,0.f},{0.f,0.f,0.f,0.f}};
    #pragma unroll
    for (int m = 0; m < 2; ++m)
        #pragma unroll
        for (int n = 0; n < 4; ++n)
            #pragma unroll
            for (int rg = 0; rg < 4; ++rg) {
                const float e = __expf(accS[m][n][rg] - gm[m][rg]);
                accS[m][n][rg] = e;
                sm[m][rg] += e;
            }
    #pragma unroll
    for (int d = 1; d < 16; d <<= 1)
        #pragma unroll
        for (int m = 0; m < 2; ++m)
            #pragma unroll
            for (int rg = 0; rg < 4; ++rg)
                sm[m][rg] += __shfl_xor(sm[m][rg], d, 64);
    if (l16 == 0) {
        #pragma unroll
        for (int m = 0; m < 2; ++m)
            #pragma unroll
            for (int rg = 0; rg < 4; ++rg)
                redsum[w][m * 16 + quad * 4 + rg] = sm[m][rg];
    }
    __syncthreads();
    float iv[2][4];
    #pragma unroll
    for (int m = 0; m < 2; ++m)
        #pragma unroll
        for (int rg = 0; rg < 4; ++rg) {
            const int row = m * 16 + quad * 4 + rg;
            float tt = redsum[0][row];
            #pragma unroll
            for (int ww = 1; ww < 8; ++ww) tt += redsum[ww][row];
            iv[m][rg] = 1.f / tt;
        }

    // ---- P -> bf16 -> swizzled LDS (arena reused; all waves past QK here)
    #pragma unroll
    for (int m = 0; m < 2; ++m)
        #pragma unroll
        for (int rg = 0; rg < 4; ++rg) {
            const int row = m * 16 + quad * 4 + rg;
            const float f = iv[m][rg];
            #pragma unroll
            for (int n = 0; n < 4; ++n) {
                const int col = w * 64 + n * 16 + l16;
                const int sw  = (((col >> 3) ^ (row & 7)) << 3) + (col & 7);
                Pl[row * 512 + sw] = (bf16_t)(accS[m][n][rg] * f);
            }
        }
    __syncthreads();

    // ---- coalesced P copy-out (un-swizzle): regular stores (want L2 keep)
    {
        const int prow = tid >> 4;            // 0..31
        const int pc0  = tid & 15;
        bf16_t* pd = Pg + (long)seg * M_SUB * M_SUB + (long)(band * 32 + prow) * M_SUB;
        #pragma unroll
        for (int j = 0; j < 4; ++j) {
            const int c = pc0 + 16 * j;       // chunk 0..63
            bf16x8 v = *(const bf16x8*)&Pl[prow * 512 + ((c ^ (prow & 7)) * 8)];
            *(bf16x8*)&pd[c * 8] = v;
        }
    }
}

// ---------------------------------------------------------------------------
// K3: PV + att scatter. One block = (seg, 32-row q-band), 8 waves,
// free-running. Reads xgT ONLY (+P stream). V ring: 4 x 32KB panels
// [512 d x 32 tok], staged 3 ahead; P-fragment reg ring-4.
// Sets of 6 vmem {2 P + 4 gload_lds}; vmcnt(12).
// ---------------------------------------------------------------------------
__global__ __launch_bounds__(512, 2) void pv_kernel(
    const bf16_t* __restrict__ Pg, const bf16_t* __restrict__ xgT,
    const int* __restrict__ hidp, float* __restrict__ out)
{
    const int off  = ((hidp[0] % RATE) + RATE) % RATE;
    const int bid0 = blockIdx.x;
    const int sub  = bid0 >> 3;
    const int seg  = (bid0 & 7) * 2 + (sub >> 4);   // same seg->XCD as qk
    const int band = sub & 15;
    const int b = seg >> 2, s = seg & 3;

    const int tid  = threadIdx.x;
    const int w    = tid >> 6;
    const int lane = tid & 63;
    const int l16  = lane & 15;
    const int quad = lane >> 4;

    __shared__ alignas(16) bf16_t Vring[4 * 16384];      // 128 KB

    const bf16_t* vsrc = xgT + ((long)seg * D_MODEL + w * 64 + (lane >> 2)) * M_SUB
                             + (((lane & 3) ^ (lane >> 4)) * 8);
    auto stageV = [&](int buf, int t) {                  // t = 0..31 (2 d-passes)
        bf16_t* dst = Vring + buf * 16384 + (w * 64) * 32;
        const bf16_t* src = vsrc + (long)(t >> 4) * 512 * M_SUB + (t & 15) * 32;
        #pragma unroll
        for (int j = 0; j < 4; ++j)
            gload16(src + j * 16 * M_SUB, dst + j * 512);
    };

    const bf16_t* pr0 = Pg + (long)seg * M_SUB * M_SUB
                           + (long)(band * 32 + l16) * M_SUB + quad * 8;
    const bf16_t* pr1 = pr0 + 16 * M_SUB;

    const int rsw = (l16 >> 2) & 3;

    floatx4 accA[2][4], accB[2][4];
    #pragma unroll
    for (int m = 0; m < 2; ++m)
        #pragma unroll
        for (int n = 0; n < 4; ++n) {
            accA[m][n] = (floatx4){0.f, 0.f, 0.f, 0.f};
            accB[m][n] = (floatx4){0.f, 0.f, 0.f, 0.f};
        }

    bf16x8 pf[4][2];
    #pragma unroll
    for (int p0 = 0; p0 < 3; ++p0) {          // prologue: sets 0..2
        pf[p0][0] = *(const bf16x8*)(pr0 + (p0 & 15) * 32);
        pf[p0][1] = *(const bf16x8*)(pr1 + (p0 & 15) * 32);
        stageV(p0, p0);
    }

    #pragma unroll
    for (int t = 0; t < 32; ++t) {
        if (t <= 29)      vwait(12);
        else if (t == 30) vwait(6);
        else              vwait(0);

        const bf16_t* Vb = Vring + (t & 3) * 16384;
        bf16x8 Bf[4];
        #pragma unroll
        for (int n = 0; n < 4; ++n) {
            const int row = w * 64 + n * 16 + l16;
            Bf[n] = *(const bf16x8*)&Vb[row * 32 + ((quad ^ rsw) * 8)];
        }
        if (t <= 28) {                         // issue set t+3
            pf[(t + 3) & 3][0] = *(const bf16x8*)(pr0 + ((t + 3) & 15) * 32);
            pf[(t + 3) & 3][1] = *(const bf16x8*)(pr1 + ((t + 3) & 15) * 32);
            stageV((t + 3) & 3, t + 3);
        }
        if (t < 16) {
            #pragma unroll
            for (int n = 0; n < 4; ++n) {
                accA[0][n] = MFMA16(pf[t & 3][0], Bf[n], accA[0][n]);
                accA[1][n] = MFMA16(pf[t & 3][1], Bf[n], accA[1][n]);
            }
        } else {
            #pragma unroll
            for (int n = 0; n < 4; ++n) {
                accB[0][n] = MFMA16(pf[t & 3][0], Bf[n], accB[0][n]);
                accB[1][n] = MFMA16(pf[t & 3][1], Bf[n], accB[1][n]);
            }
        }
    }

    // ---- att scatter (nontemporal)
    float* obase = out + (long)b * NTOK * D_MODEL;
    #pragma unroll
    for (int m = 0; m < 2; ++m)
        #pragma unroll
        for (int rg = 0; rg < 4; ++rg) {
            const long tok = (long)s * SEG_W + off + 4L * (band * 32 + m * 16 + quad * 4 + rg);
            float* orow = obase + tok * D_MODEL;
            #pragma unroll
            for (int n = 0; n < 4; ++n) {
                const int d = w * 64 + n * 16 + l16;
                __builtin_nontemporal_store(accA[m][n][rg], orow + d);
                __builtin_nontemporal_store(accB[m][n][rg], orow + 512 + d);
            }
        }
}

extern "C" void kernel_launch(void* const* d_in, const int* in_sizes, int n_in,
                              void* d_out, int out_size, void* d_ws, size_t ws_size,
                              hipStream_t stream) {
    const float* x   = (const float*)d_in[0];
    const int*   hid = (const int*)d_in[1];
    float*       out = (float*)d_out;
    bf16_t* xg  = (bf16_t*)d_ws;
    bf16_t* xgT = xg + XG_ELEMS;
    bf16_t* Pg  = xgT + XG_ELEMS;     // total ws: 16.78*2 + 8.39 = 41.94 MB

    gather_kernel<<<dim3(2048), dim3(256), 0, stream>>>(x, hid, xg, xgT, out);
    qk_kernel<<<dim3(256), dim3(512), 0, stream>>>(xg, Pg);
    pv_kernel<<<dim3(256), dim3(512), 0, stream>>>(Pg, xgT, hid, out);
}

// Round 7
// 243.009 us; speedup vs baseline: 1.2267x; 1.1098x over previous
//
#include <hip/hip_runtime.h>
#include <hip/hip_bf16.h>

// DilatedAttention (b=4, n=8192, d=1024, w=2048, r=4):
// 16 independent 512x512 self-attentions at d=1024 over gathered tokens.
// alphas==1 (idx unique), so output = scatter(att) + zero-fill.
//
// R7 = R4 (best measured structure: fused attn, free-running waves,
// K ring-4 staged 3 ahead w/ counted vmcnt, V ring-3) with:
//  (a) the 100MB zero-fill interleaved INTO the PV loop (2 nontemporal
//      float4/thread/iter, iters 0..23) so the HBM store drain overlaps
//      PV compute instead of serializing in the epilogue at 1 block/CU.
//      vmcnt waits re-derived counting the store slots (in-order vmcnt).
//  (b) s_setprio(1) around MFMA clusters (free-running waves = T5 regime).
//  (c) epilogue reduced to the 34MB att scatter.
// LDS 130KB: QK: K 4x32K [0,128K) | red [128K,130K); PV: P [0,32K),
// V 3x32K [32K,128K) (region reuse protected by softmax __syncthreads).

typedef __bf16 bf16_t;
typedef __bf16 bf16x8 __attribute__((ext_vector_type(8)));
typedef float floatx4 __attribute__((ext_vector_type(4)));

#define D_MODEL 1024
#define SEG_W   2048
#define RATE    4
#define M_SUB   512
#define NTOK    8192
#define NSEGT   16
#define XG_ELEMS ((long)NSEGT * M_SUB * D_MODEL)

__device__ __forceinline__ void gload16(const bf16_t* g, bf16_t* l) {
    __builtin_amdgcn_global_load_lds(
        (const __attribute__((address_space(1))) void*)g,
        (__attribute__((address_space(3))) void*)l, 16, 0, 0);
}

#define MFMA16(a, b, c) __builtin_amdgcn_mfma_f32_16x16x32_bf16((a), (b), (c), 0, 0, 0)

__device__ __forceinline__ void vwait(int n) {
    switch (n) {
    case 0:  asm volatile("s_waitcnt vmcnt(0)"  ::: "memory"); break;
    case 4:  asm volatile("s_waitcnt vmcnt(4)"  ::: "memory"); break;
    case 6:  asm volatile("s_waitcnt vmcnt(6)"  ::: "memory"); break;
    case 8:  asm volatile("s_waitcnt vmcnt(8)"  ::: "memory"); break;
    case 10: asm volatile("s_waitcnt vmcnt(10)" ::: "memory"); break;
    case 12: asm volatile("s_waitcnt vmcnt(12)" ::: "memory"); break;
    case 14: asm volatile("s_waitcnt vmcnt(14)" ::: "memory"); break;
    }
}

// ---------------------------------------------------------------------------
// K1: gather x[b, s*2048 + off + 4i, :] -> xg bf16 [seg][i][d]
//                                       -> xgT bf16 [seg][d][i]
// ---------------------------------------------------------------------------
__global__ __launch_bounds__(256) void gather_kernel(
    const float* __restrict__ x, const int* __restrict__ hidp,
    bf16_t* __restrict__ xg, bf16_t* __restrict__ xgT)
{
    const int off = ((hidp[0] % RATE) + RATE) % RATE;
    const int bid = blockIdx.x;
    const int seg = bid >> 7;
    const int rem = bid & 127;
    const int it  = rem >> 4;
    const int dt  = rem & 15;
    const int b   = seg >> 2, s = seg & 3;

    __shared__ ushort tile[64][65];

    const int t  = threadIdx.x;
    const int r  = t >> 2;
    const int cq = (t & 3) << 4;

    union U8 { bf16x8 v; ushort u[8]; };

    {
        const int  i   = it * 64 + r;
        const long tok = (long)s * SEG_W + off + 4L * i;
        const float* src = x + ((long)b * NTOK + tok) * D_MODEL + dt * 64 + cq;
        float4 f0 = ((const float4*)src)[0];
        float4 f1 = ((const float4*)src)[1];
        float4 f2 = ((const float4*)src)[2];
        float4 f3 = ((const float4*)src)[3];
        U8 lo, hi;
        lo.v[0]=(bf16_t)f0.x; lo.v[1]=(bf16_t)f0.y; lo.v[2]=(bf16_t)f0.z; lo.v[3]=(bf16_t)f0.w;
        lo.v[4]=(bf16_t)f1.x; lo.v[5]=(bf16_t)f1.y; lo.v[6]=(bf16_t)f1.z; lo.v[7]=(bf16_t)f1.w;
        hi.v[0]=(bf16_t)f2.x; hi.v[1]=(bf16_t)f2.y; hi.v[2]=(bf16_t)f2.z; hi.v[3]=(bf16_t)f2.w;
        hi.v[4]=(bf16_t)f3.x; hi.v[5]=(bf16_t)f3.y; hi.v[6]=(bf16_t)f3.z; hi.v[7]=(bf16_t)f3.w;
        bf16_t* dstg = xg + ((long)seg * M_SUB + i) * D_MODEL + dt * 64 + cq;
        *(bf16x8*)(dstg)     = lo.v;
        *(bf16x8*)(dstg + 8) = hi.v;
        #pragma unroll
        for (int j = 0; j < 8; ++j) { tile[r][cq + j] = lo.u[j]; tile[r][cq + 8 + j] = hi.u[j]; }
    }
    __syncthreads();
    {
        const int dc = r;
        const int iq = cq;
        U8 o0, o1;
        #pragma unroll
        for (int j = 0; j < 8; ++j) { o0.u[j] = tile[iq + j][dc]; o1.u[j] = tile[iq + 8 + j][dc]; }
        bf16_t* dstT = xgT + ((long)seg * D_MODEL + dt * 64 + dc) * M_SUB + it * 64 + iq;
        *(bf16x8*)(dstT)     = o0.v;
        *(bf16x8*)(dstT + 8) = o1.v;
    }
}

// ---------------------------------------------------------------------------
// K2: fused attention. One block = one (seg, 32-row q-band), 8 waves,
// free-running (per-wave panel slices; cross-wave sync only at softmax/P).
// ---------------------------------------------------------------------------
__global__ __launch_bounds__(512, 2) void attn_kernel(
    const bf16_t* __restrict__ xg, const bf16_t* __restrict__ xgT,
    const int* __restrict__ hidp, float* __restrict__ out)
{
    const int off  = ((hidp[0] % RATE) + RATE) % RATE;
    const int bid0 = blockIdx.x;
    const int sub  = bid0 >> 3;
    const int seg  = (bid0 & 7) * 2 + (sub >> 4);   // seg->XCD locality
    const int band = sub & 15;
    const int b = seg >> 2, s = seg & 3;

    const int tid  = threadIdx.x;
    const int w    = tid >> 6;
    const int lane = tid & 63;
    const int l16  = lane & 15;
    const int quad = lane >> 4;

    __shared__ alignas(16) char arena[133120];           // 130 KB
    bf16_t* Kring = (bf16_t*)arena;                      // QK: 4 x 32K [0,128K)
    float (*redmax)[32] = (float(*)[32])(arena + 131072);
    float (*redsum)[32] = (float(*)[32])(arena + 132096);
    bf16_t* Pl    = (bf16_t*)arena;                      // PV: [0,32K)
    bf16_t* Vring = (bf16_t*)(arena + 32768);            // PV: 3 x 32K

    const bf16_t* xs = xg + (long)seg * M_SUB * D_MODEL;
    float* obase = out + (long)b * NTOK * D_MODEL;

    const bf16_t* qr0 = xs + (long)(band * 32 + l16) * D_MODEL + quad * 8;
    const bf16_t* qr1 = qr0 + 16 * D_MODEL;

    const bf16_t* ksrc = xs + (long)(w * 64 + (lane >> 2)) * D_MODEL
                            + (((lane & 3) ^ (lane >> 4)) * 8);
    auto stageK = [&](int buf, int t) {
        bf16_t* dst = Kring + buf * 16384 + (w * 64) * 32;
        const bf16_t* src = ksrc + t * 32;
        #pragma unroll
        for (int j = 0; j < 4; ++j)
            gload16(src + j * 16 * D_MODEL, dst + j * 512);
    };

    const bf16_t* vsrc = xgT + ((long)seg * D_MODEL + w * 64 + (lane >> 2)) * M_SUB
                             + (((lane & 3) ^ (lane >> 4)) * 8);
    auto stageV = [&](int buf, int t) {                  // t = 0..31 (2 d-passes)
        bf16_t* dst = Vring + buf * 16384 + (w * 64) * 32;
        const bf16_t* src = vsrc + (long)(t >> 4) * 512 * M_SUB + (t & 15) * 32;
        #pragma unroll
        for (int j = 0; j < 4; ++j)
            gload16(src + j * 16 * M_SUB, dst + j * 512);
    };

    // interleaved zero-fill: iter t (0..23) zeroes 4 rows of the band's 96
    // non-idx rows, full 1024 cols (2 x float4 per thread).
    auto zstore = [&](int t) {
        const floatx4 z = {0.f, 0.f, 0.f, 0.f};
        const int r2 = tid >> 7;              // 0..3
        const int j  = t * 4 + r2;            // 0..95
        const int q  = j / 3, e = j - 3 * (j / 3);
        const int delta = e + (e >= off ? 1 : 0);
        const long tok = (long)s * SEG_W + 4L * (band * 32 + q) + delta;
        float* dst = obase + tok * D_MODEL + (tid & 127) * 4;
        __builtin_nontemporal_store(z, (floatx4*)dst);
        __builtin_nontemporal_store(z, (floatx4*)(dst + 512));
    };

    const int rsw = (l16 >> 2) & 3;   // panel read swizzle key

    // ================= QK: 32 tiles of BK=32, ring-4, 3 sets ahead ========
    floatx4 accS[2][4];
    #pragma unroll
    for (int m = 0; m < 2; ++m)
        #pragma unroll
        for (int n = 0; n < 4; ++n) accS[m][n] = (floatx4){0.f, 0.f, 0.f, 0.f};

    bf16x8 qf[4][2];
    #pragma unroll
    for (int p0 = 0; p0 < 3; ++p0) {          // prologue: sets 0..2
        qf[p0][0] = *(const bf16x8*)(qr0 + p0 * 32);
        qf[p0][1] = *(const bf16x8*)(qr1 + p0 * 32);
        stageK(p0, p0);
    }

    #pragma unroll
    for (int t = 0; t < 32; ++t) {
        // set = {2 Q, 4 stage}; keep 2 sets (12) in flight -> set t landed
        if (t <= 29)      vwait(12);
        else if (t == 30) vwait(6);
        else              vwait(0);

        const bf16_t* Kb = Kring + (t & 3) * 16384;
        bf16x8 Bf[4];
        #pragma unroll
        for (int n = 0; n < 4; ++n) {
            const int row = w * 64 + n * 16 + l16;
            Bf[n] = *(const bf16x8*)&Kb[row * 32 + ((quad ^ rsw) * 8)];
        }
        if (t <= 28) {                         // issue set t+3
            qf[(t + 3) & 3][0] = *(const bf16x8*)(qr0 + (t + 3) * 32);
            qf[(t + 3) & 3][1] = *(const bf16x8*)(qr1 + (t + 3) * 32);
            stageK((t + 3) & 3, t + 3);
        }
        __builtin_amdgcn_s_setprio(1);
        #pragma unroll
        for (int n = 0; n < 4; ++n) {
            accS[0][n] = MFMA16(qf[t & 3][0], Bf[n], accS[0][n]);
            accS[1][n] = MFMA16(qf[t & 3][1], Bf[n], accS[1][n]);
        }
        __builtin_amdgcn_s_setprio(0);
    }

    // ================= softmax (f32, cross-wave via LDS) =================
    #pragma unroll
    for (int m = 0; m < 2; ++m)
        #pragma unroll
        for (int n = 0; n < 4; ++n)
            #pragma unroll
            for (int rg = 0; rg < 4; ++rg) accS[m][n][rg] *= 0.03125f;  // 1/sqrt(1024)

    float mx[2][4];
    #pragma unroll
    for (int m = 0; m < 2; ++m)
        #pragma unroll
        for (int rg = 0; rg < 4; ++rg)
            mx[m][rg] = fmaxf(fmaxf(accS[m][0][rg], accS[m][1][rg]),
                              fmaxf(accS[m][2][rg], accS[m][3][rg]));
    #pragma unroll
    for (int d = 1; d < 16; d <<= 1)
        #pragma unroll
        for (int m = 0; m < 2; ++m)
            #pragma unroll
            for (int rg = 0; rg < 4; ++rg)
                mx[m][rg] = fmaxf(mx[m][rg], __shfl_xor(mx[m][rg], d, 64));
    if (l16 == 0) {
        #pragma unroll
        for (int m = 0; m < 2; ++m)
            #pragma unroll
            for (int rg = 0; rg < 4; ++rg)
                redmax[w][m * 16 + quad * 4 + rg] = mx[m][rg];
    }
    __syncthreads();
    float gm[2][4];
    #pragma unroll
    for (int m = 0; m < 2; ++m)
        #pragma unroll
        for (int rg = 0; rg < 4; ++rg) {
            const int row = m * 16 + quad * 4 + rg;
            float g = redmax[0][row];
            #pragma unroll
            for (int ww = 1; ww < 8; ++ww) g = fmaxf(g, redmax[ww][row]);
            gm[m][rg] = g;
        }
    float sm[2][4] = {{0.f,0.f,0.f,0.f},{0.f,0.f,0.f,0.f}};
    #pragma unroll
    for (int m = 0; m < 2; ++m)
        #pragma unroll
        for (int n = 0; n < 4; ++n)
            #pragma unroll
            for (int rg = 0; rg < 4; ++rg) {
                const float e = __expf(accS[m][n][rg] - gm[m][rg]);
                accS[m][n][rg] = e;
                sm[m][rg] += e;
            }
    #pragma unroll
    for (int d = 1; d < 16; d <<= 1)
        #pragma unroll
        for (int m = 0; m < 2; ++m)
            #pragma unroll
            for (int rg = 0; rg < 4; ++rg)
                sm[m][rg] += __shfl_xor(sm[m][rg], d, 64);
    if (l16 == 0) {
        #pragma unroll
        for (int m = 0; m < 2; ++m)
            #pragma unroll
            for (int rg = 0; rg < 4; ++rg)
                redsum[w][m * 16 + quad * 4 + rg] = sm[m][rg];
    }
    __syncthreads();
    float iv[2][4];
    #pragma unroll
    for (int m = 0; m < 2; ++m)
        #pragma unroll
        for (int rg = 0; rg < 4; ++rg) {
            const int row = m * 16 + quad * 4 + rg;
            float tt = redsum[0][row];
            #pragma unroll
            for (int ww = 1; ww < 8; ++ww) tt += redsum[ww][row];
            iv[m][rg] = 1.f / tt;
        }

    // ---- issue first 3 V sets (overlap with P-store), then P -> LDS
    stageV(0, 0); stageV(1, 1); stageV(2, 2);

    #pragma unroll
    for (int m = 0; m < 2; ++m)
        #pragma unroll
        for (int rg = 0; rg < 4; ++rg) {
            const int row = m * 16 + quad * 4 + rg;
            const float f = iv[m][rg];
            #pragma unroll
            for (int n = 0; n < 4; ++n) {
                const int col = w * 64 + n * 16 + l16;
                const int sw  = (((col >> 3) ^ (row & 7)) << 3) + (col & 7);
                Pl[row * 512 + sw] = (bf16_t)(accS[m][n][rg] * f);
            }
        }
    asm volatile("s_waitcnt lgkmcnt(0)" ::: "memory");  // P visible; V DMA live
    __builtin_amdgcn_s_barrier();
    __builtin_amdgcn_sched_barrier(0);

    // ================= PV: 32 linear tiles (2 d-passes x 16), ring-3 ======
    // Per iter: vwait(exact younger-op count) ; ds_read P+V ; MFMA ;
    // stage(t+3) ; 2 zero stores (iters 0..23). In-order vmcnt counting:
    // N[t] = #vmem ops issued after V-set t = {8,10,12,14x22,12,10,8,8,8,4,0}.
    floatx4 accA[2][4], accB[2][4];
    #pragma unroll
    for (int m = 0; m < 2; ++m)
        #pragma unroll
        for (int n = 0; n < 4; ++n) {
            accA[m][n] = (floatx4){0.f, 0.f, 0.f, 0.f};
            accB[m][n] = (floatx4){0.f, 0.f, 0.f, 0.f};
        }

    #pragma unroll
    for (int t = 0; t < 32; ++t) {
        if      (t == 0)  vwait(8);
        else if (t == 1)  vwait(10);
        else if (t == 2)  vwait(12);
        else if (t <= 24) vwait(14);
        else if (t == 25) vwait(12);
        else if (t == 26) vwait(10);
        else if (t <= 29) vwait(8);
        else if (t == 30) vwait(4);
        else              vwait(0);

        const bf16_t* Vb = Vring + (t % 3) * 16384;
        bf16x8 Af[2], Bf[4];
        const int ch = ((t & 15) * 4 + quad) ^ (l16 & 7);
        #pragma unroll
        for (int m = 0; m < 2; ++m)
            Af[m] = *(const bf16x8*)&Pl[(m * 16 + l16) * 512 + ch * 8];
        #pragma unroll
        for (int n = 0; n < 4; ++n) {
            const int row = w * 64 + n * 16 + l16;
            Bf[n] = *(const bf16x8*)&Vb[row * 32 + ((quad ^ rsw) * 8)];
        }
        __builtin_amdgcn_s_setprio(1);
        if (t < 16) {
            #pragma unroll
            for (int n = 0; n < 4; ++n) {
                accA[0][n] = MFMA16(Af[0], Bf[n], accA[0][n]);
                accA[1][n] = MFMA16(Af[1], Bf[n], accA[1][n]);
            }
        } else {
            #pragma unroll
            for (int n = 0; n < 4; ++n) {
                accB[0][n] = MFMA16(Af[0], Bf[n], accB[0][n]);
                accB[1][n] = MFMA16(Af[1], Bf[n], accB[1][n]);
            }
        }
        __builtin_amdgcn_s_setprio(0);
        __builtin_amdgcn_sched_barrier(0);     // pin: MFMA | stage | stores
        if (t <= 28) stageV((t + 3) % 3, t + 3);
        __builtin_amdgcn_sched_barrier(0);
        if (t <= 23) zstore(t);
    }

    // ================= epilogue: att scatter only =========================
    #pragma unroll
    for (int m = 0; m < 2; ++m)
        #pragma unroll
        for (int rg = 0; rg < 4; ++rg) {
            const long tok = (long)s * SEG_W + off + 4L * (band * 32 + m * 16 + quad * 4 + rg);
            float* orow = obase + tok * D_MODEL;
            #pragma unroll
            for (int n = 0; n < 4; ++n) {
                const int d = w * 64 + n * 16 + l16;
                __builtin_nontemporal_store(accA[m][n][rg], orow + d);
                __builtin_nontemporal_store(accB[m][n][rg], orow + 512 + d);
            }
        }
}

extern "C" void kernel_launch(void* const* d_in, const int* in_sizes, int n_in,
                              void* d_out, int out_size, void* d_ws, size_t ws_size,
                              hipStream_t stream) {
    const float* x   = (const float*)d_in[0];
    const int*   hid = (const int*)d_in[1];
    float*       out = (float*)d_out;
    bf16_t* xg  = (bf16_t*)d_ws;
    bf16_t* xgT = xg + XG_ELEMS;      // ws: 33.6 MB

    gather_kernel<<<dim3(2048), dim3(256), 0, stream>>>(x, hid, xg, xgT);
    attn_kernel<<<dim3(256), dim3(512), 0, stream>>>(xg, xgT, hid, out);
}

// Round 8
// 242.226 us; speedup vs baseline: 1.2307x; 1.0032x over previous
//
#include <hip/hip_runtime.h>
#include <hip/hip_bf16.h>

// DilatedAttention (b=4, n=8192, d=1024, w=2048, r=4):
// 16 independent 512x512 self-attentions at d=1024 over gathered tokens.
// alphas==1 (idx unique), so output = scatter(att) + zero-fill.
//
// R8 = R7 (best: fused attn, free-running waves, K ring-4 / V ring-3 with
// counted vmcnt, zero-fill overlap, setprio) with the HBM write stream
// fully flattened across both compute phases:
//  (a) zero-fill split: rows 0-47 during QK iters 8-31 (1 f4/thr/iter),
//      rows 48-95 during PV iters 0-23 (QK's write pipe was idle).
//  (b) accA scatter (17MB) interleaved into PV iters 16-31 (2 f32/thr/iter);
//      epilogue is accB only.
//  (c) all vmcnt waits re-derived with exact in-order op counting:
//      QK N[t] = {12 x9, 13, 14, 15 x19, 9, 3}
//      PV N[t] = {8, 9, 10, 11 x14, 13, 15, 17 x6, 16, 15, 14 x3, 10, 6}.
// LDS 130KB unchanged.

typedef __bf16 bf16_t;
typedef __bf16 bf16x8 __attribute__((ext_vector_type(8)));
typedef float floatx4 __attribute__((ext_vector_type(4)));

#define D_MODEL 1024
#define SEG_W   2048
#define RATE    4
#define M_SUB   512
#define NTOK    8192
#define NSEGT   16
#define XG_ELEMS ((long)NSEGT * M_SUB * D_MODEL)

__device__ __forceinline__ void gload16(const bf16_t* g, bf16_t* l) {
    __builtin_amdgcn_global_load_lds(
        (const __attribute__((address_space(1))) void*)g,
        (__attribute__((address_space(3))) void*)l, 16, 0, 0);
}

#define MFMA16(a, b, c) __builtin_amdgcn_mfma_f32_16x16x32_bf16((a), (b), (c), 0, 0, 0)

__device__ __forceinline__ void vwait(int n) {
    switch (n) {
    case 0:  asm volatile("s_waitcnt vmcnt(0)"  ::: "memory"); break;
    case 3:  asm volatile("s_waitcnt vmcnt(3)"  ::: "memory"); break;
    case 6:  asm volatile("s_waitcnt vmcnt(6)"  ::: "memory"); break;
    case 8:  asm volatile("s_waitcnt vmcnt(8)"  ::: "memory"); break;
    case 9:  asm volatile("s_waitcnt vmcnt(9)"  ::: "memory"); break;
    case 10: asm volatile("s_waitcnt vmcnt(10)" ::: "memory"); break;
    case 11: asm volatile("s_waitcnt vmcnt(11)" ::: "memory"); break;
    case 12: asm volatile("s_waitcnt vmcnt(12)" ::: "memory"); break;
    case 13: asm volatile("s_waitcnt vmcnt(13)" ::: "memory"); break;
    case 14: asm volatile("s_waitcnt vmcnt(14)" ::: "memory"); break;
    case 15: asm volatile("s_waitcnt vmcnt(15)" ::: "memory"); break;
    case 16: asm volatile("s_waitcnt vmcnt(16)" ::: "memory"); break;
    case 17: asm volatile("s_waitcnt vmcnt(17)" ::: "memory"); break;
    }
}

// ---------------------------------------------------------------------------
// K1: gather x[b, s*2048 + off + 4i, :] -> xg bf16 [seg][i][d]
//                                       -> xgT bf16 [seg][d][i]
// ---------------------------------------------------------------------------
__global__ __launch_bounds__(256) void gather_kernel(
    const float* __restrict__ x, const int* __restrict__ hidp,
    bf16_t* __restrict__ xg, bf16_t* __restrict__ xgT)
{
    const int off = ((hidp[0] % RATE) + RATE) % RATE;
    const int bid = blockIdx.x;
    const int seg = bid >> 7;
    const int rem = bid & 127;
    const int it  = rem >> 4;
    const int dt  = rem & 15;
    const int b   = seg >> 2, s = seg & 3;

    __shared__ ushort tile[64][65];

    const int t  = threadIdx.x;
    const int r  = t >> 2;
    const int cq = (t & 3) << 4;

    union U8 { bf16x8 v; ushort u[8]; };

    {
        const int  i   = it * 64 + r;
        const long tok = (long)s * SEG_W + off + 4L * i;
        const float* src = x + ((long)b * NTOK + tok) * D_MODEL + dt * 64 + cq;
        float4 f0 = ((const float4*)src)[0];
        float4 f1 = ((const float4*)src)[1];
        float4 f2 = ((const float4*)src)[2];
        float4 f3 = ((const float4*)src)[3];
        U8 lo, hi;
        lo.v[0]=(bf16_t)f0.x; lo.v[1]=(bf16_t)f0.y; lo.v[2]=(bf16_t)f0.z; lo.v[3]=(bf16_t)f0.w;
        lo.v[4]=(bf16_t)f1.x; lo.v[5]=(bf16_t)f1.y; lo.v[6]=(bf16_t)f1.z; lo.v[7]=(bf16_t)f1.w;
        hi.v[0]=(bf16_t)f2.x; hi.v[1]=(bf16_t)f2.y; hi.v[2]=(bf16_t)f2.z; hi.v[3]=(bf16_t)f2.w;
        hi.v[4]=(bf16_t)f3.x; hi.v[5]=(bf16_t)f3.y; hi.v[6]=(bf16_t)f3.z; hi.v[7]=(bf16_t)f3.w;
        bf16_t* dstg = xg + ((long)seg * M_SUB + i) * D_MODEL + dt * 64 + cq;
        *(bf16x8*)(dstg)     = lo.v;
        *(bf16x8*)(dstg + 8) = hi.v;
        #pragma unroll
        for (int j = 0; j < 8; ++j) { tile[r][cq + j] = lo.u[j]; tile[r][cq + 8 + j] = hi.u[j]; }
    }
    __syncthreads();
    {
        const int dc = r;
        const int iq = cq;
        U8 o0, o1;
        #pragma unroll
        for (int j = 0; j < 8; ++j) { o0.u[j] = tile[iq + j][dc]; o1.u[j] = tile[iq + 8 + j][dc]; }
        bf16_t* dstT = xgT + ((long)seg * D_MODEL + dt * 64 + dc) * M_SUB + it * 64 + iq;
        *(bf16x8*)(dstT)     = o0.v;
        *(bf16x8*)(dstT + 8) = o1.v;
    }
}

// ---------------------------------------------------------------------------
// K2: fused attention. One block = one (seg, 32-row q-band), 8 waves,
// free-running (per-wave panel slices; cross-wave sync only at softmax/P).
// ---------------------------------------------------------------------------
__global__ __launch_bounds__(512, 2) void attn_kernel(
    const bf16_t* __restrict__ xg, const bf16_t* __restrict__ xgT,
    const int* __restrict__ hidp, float* __restrict__ out)
{
    const int off  = ((hidp[0] % RATE) + RATE) % RATE;
    const int bid0 = blockIdx.x;
    const int sub  = bid0 >> 3;
    const int seg  = (bid0 & 7) * 2 + (sub >> 4);   // seg->XCD locality
    const int band = sub & 15;
    const int b = seg >> 2, s = seg & 3;

    const int tid  = threadIdx.x;
    const int w    = tid >> 6;
    const int lane = tid & 63;
    const int l16  = lane & 15;
    const int quad = lane >> 4;

    __shared__ alignas(16) char arena[133120];           // 130 KB
    bf16_t* Kring = (bf16_t*)arena;                      // QK: 4 x 32K [0,128K)
    float (*redmax)[32] = (float(*)[32])(arena + 131072);
    float (*redsum)[32] = (float(*)[32])(arena + 132096);
    bf16_t* Pl    = (bf16_t*)arena;                      // PV: [0,32K)
    bf16_t* Vring = (bf16_t*)(arena + 32768);            // PV: 3 x 32K

    const bf16_t* xs = xg + (long)seg * M_SUB * D_MODEL;
    float* obase = out + (long)b * NTOK * D_MODEL;

    const bf16_t* qr0 = xs + (long)(band * 32 + l16) * D_MODEL + quad * 8;
    const bf16_t* qr1 = qr0 + 16 * D_MODEL;

    const bf16_t* ksrc = xs + (long)(w * 64 + (lane >> 2)) * D_MODEL
                            + (((lane & 3) ^ (lane >> 4)) * 8);
    auto stageK = [&](int buf, int t) {
        bf16_t* dst = Kring + buf * 16384 + (w * 64) * 32;
        const bf16_t* src = ksrc + t * 32;
        #pragma unroll
        for (int j = 0; j < 4; ++j)
            gload16(src + j * 16 * D_MODEL, dst + j * 512);
    };

    const bf16_t* vsrc = xgT + ((long)seg * D_MODEL + w * 64 + (lane >> 2)) * M_SUB
                             + (((lane & 3) ^ (lane >> 4)) * 8);
    auto stageV = [&](int buf, int t) {                  // t = 0..31 (2 d-passes)
        bf16_t* dst = Vring + buf * 16384 + (w * 64) * 32;
        const bf16_t* src = vsrc + (long)(t >> 4) * 512 * M_SUB + (t & 15) * 32;
        #pragma unroll
        for (int j = 0; j < 4; ++j)
            gload16(src + j * 16 * M_SUB, dst + j * 512);
    };

    // zero-fill: one call zeroes 2 full non-idx rows (rows j0, j0+1 of the
    // band's 96); 512 thr x 1 float4 = 8 KB = 2 rows. 1 vmem op/thread.
    auto zstore = [&](int j0) {
        const floatx4 z = {0.f, 0.f, 0.f, 0.f};
        const int j = j0 + (tid >> 8);        // j0..j0+1
        const int q = j / 3, e = j - 3 * (j / 3);
        const int delta = e + (e >= off ? 1 : 0);
        const long tok = (long)s * SEG_W + 4L * (band * 32 + q) + delta;
        float* dst = obase + tok * D_MODEL + (tid & 255) * 4;
        __builtin_nontemporal_store(z, (floatx4*)dst);
    };

    const int rsw = (l16 >> 2) & 3;   // panel read swizzle key

    // ================= QK: 32 tiles of BK=32, ring-4, 3 sets ahead ========
    // + zero rows 0..47 during iters 8..31 (write pipe otherwise idle here).
    floatx4 accS[2][4];
    #pragma unroll
    for (int m = 0; m < 2; ++m)
        #pragma unroll
        for (int n = 0; n < 4; ++n) accS[m][n] = (floatx4){0.f, 0.f, 0.f, 0.f};

    bf16x8 qf[4][2];
    #pragma unroll
    for (int p0 = 0; p0 < 3; ++p0) {          // prologue: sets 0..2
        qf[p0][0] = *(const bf16x8*)(qr0 + p0 * 32);
        qf[p0][1] = *(const bf16x8*)(qr1 + p0 * 32);
        stageK(p0, p0);
    }

    #pragma unroll
    for (int t = 0; t < 32; ++t) {
        // N[t] = exact count of vmem ops issued after set t's last load
        if      (t <= 8)  vwait(12);
        else if (t == 9)  vwait(13);
        else if (t == 10) vwait(14);
        else if (t <= 29) vwait(15);
        else if (t == 30) vwait(9);
        else              vwait(3);

        const bf16_t* Kb = Kring + (t & 3) * 16384;
        bf16x8 Bf[4];
        #pragma unroll
        for (int n = 0; n < 4; ++n) {
            const int row = w * 64 + n * 16 + l16;
            Bf[n] = *(const bf16x8*)&Kb[row * 32 + ((quad ^ rsw) * 8)];
        }
        if (t <= 28) {                         // issue set t+3
            qf[(t + 3) & 3][0] = *(const bf16x8*)(qr0 + (t + 3) * 32);
            qf[(t + 3) & 3][1] = *(const bf16x8*)(qr1 + (t + 3) * 32);
            stageK((t + 3) & 3, t + 3);
        }
        __builtin_amdgcn_s_setprio(1);
        #pragma unroll
        for (int n = 0; n < 4; ++n) {
            accS[0][n] = MFMA16(qf[t & 3][0], Bf[n], accS[0][n]);
            accS[1][n] = MFMA16(qf[t & 3][1], Bf[n], accS[1][n]);
        }
        __builtin_amdgcn_s_setprio(0);
        __builtin_amdgcn_sched_barrier(0);     // pin: stage | zstore order
        if (t >= 8) zstore((t - 8) * 2);       // rows 0..47
    }

    // ================= softmax (f32, cross-wave via LDS) =================
    #pragma unroll
    for (int m = 0; m < 2; ++m)
        #pragma unroll
        for (int n = 0; n < 4; ++n)
            #pragma unroll
            for (int rg = 0; rg < 4; ++rg) accS[m][n][rg] *= 0.03125f;  // 1/sqrt(1024)

    float mx[2][4];
    #pragma unroll
    for (int m = 0; m < 2; ++m)
        #pragma unroll
        for (int rg = 0; rg < 4; ++rg)
            mx[m][rg] = fmaxf(fmaxf(accS[m][0][rg], accS[m][1][rg]),
                              fmaxf(accS[m][2][rg], accS[m][3][rg]));
    #pragma unroll
    for (int d = 1; d < 16; d <<= 1)
        #pragma unroll
        for (int m = 0; m < 2; ++m)
            #pragma unroll
            for (int rg = 0; rg < 4; ++rg)
                mx[m][rg] = fmaxf(mx[m][rg], __shfl_xor(mx[m][rg], d, 64));
    if (l16 == 0) {
        #pragma unroll
        for (int m = 0; m < 2; ++m)
            #pragma unroll
            for (int rg = 0; rg < 4; ++rg)
                redmax[w][m * 16 + quad * 4 + rg] = mx[m][rg];
    }
    __syncthreads();
    float gm[2][4];
    #pragma unroll
    for (int m = 0; m < 2; ++m)
        #pragma unroll
        for (int rg = 0; rg < 4; ++rg) {
            const int row = m * 16 + quad * 4 + rg;
            float g = redmax[0][row];
            #pragma unroll
            for (int ww = 1; ww < 8; ++ww) g = fmaxf(g, redmax[ww][row]);
            gm[m][rg] = g;
        }
    float sm[2][4] = {{0.f,0.f,0.f,0.f},{0.f,0.f,0.f,0.f}};
    #pragma unroll
    for (int m = 0; m < 2; ++m)
        #pragma unroll
        for (int n = 0; n < 4; ++n)
            #pragma unroll
            for (int rg = 0; rg < 4; ++rg) {
                const float e = __expf(accS[m][n][rg] - gm[m][rg]);
                accS[m][n][rg] = e;
                sm[m][rg] += e;
            }
    #pragma unroll
    for (int d = 1; d < 16; d <<= 1)
        #pragma unroll
        for (int m = 0; m < 2; ++m)
            #pragma unroll
            for (int rg = 0; rg < 4; ++rg)
                sm[m][rg] += __shfl_xor(sm[m][rg], d, 64);
    if (l16 == 0) {
        #pragma unroll
        for (int m = 0; m < 2; ++m)
            #pragma unroll
            for (int rg = 0; rg < 4; ++rg)
                redsum[w][m * 16 + quad * 4 + rg] = sm[m][rg];
    }
    __syncthreads();
    float iv[2][4];
    #pragma unroll
    for (int m = 0; m < 2; ++m)
        #pragma unroll
        for (int rg = 0; rg < 4; ++rg) {
            const int row = m * 16 + quad * 4 + rg;
            float tt = redsum[0][row];
            #pragma unroll
            for (int ww = 1; ww < 8; ++ww) tt += redsum[ww][row];
            iv[m][rg] = 1.f / tt;
        }

    // ---- issue first 3 V sets (overlap with P-store), then P -> LDS
    stageV(0, 0); stageV(1, 1); stageV(2, 2);

    #pragma unroll
    for (int m = 0; m < 2; ++m)
        #pragma unroll
        for (int rg = 0; rg < 4; ++rg) {
            const int row = m * 16 + quad * 4 + rg;
            const float f = iv[m][rg];
            #pragma unroll
            for (int n = 0; n < 4; ++n) {
                const int col = w * 64 + n * 16 + l16;
                const int sw  = (((col >> 3) ^ (row & 7)) << 3) + (col & 7);
                Pl[row * 512 + sw] = (bf16_t)(accS[m][n][rg] * f);
            }
        }
    asm volatile("s_waitcnt lgkmcnt(0)" ::: "memory");  // P visible; V DMA live
    __builtin_amdgcn_s_barrier();
    __builtin_amdgcn_sched_barrier(0);

    // ================= PV: 32 linear tiles (2 d-passes x 16), ring-3 ======
    // Per iter: vwait(exact) ; ds_read P+V ; MFMA ; stage(t+3) ;
    // zstore rows 48..95 (t<=23) ; accA scatter (t>=16, 2 f32/thr).
    floatx4 accA[2][4], accB[2][4];
    #pragma unroll
    for (int m = 0; m < 2; ++m)
        #pragma unroll
        for (int n = 0; n < 4; ++n) {
            accA[m][n] = (floatx4){0.f, 0.f, 0.f, 0.f};
            accB[m][n] = (floatx4){0.f, 0.f, 0.f, 0.f};
        }

    #pragma unroll
    for (int t = 0; t < 32; ++t) {
        if      (t == 0)  vwait(8);
        else if (t == 1)  vwait(9);
        else if (t == 2)  vwait(10);
        else if (t <= 16) vwait(11);
        else if (t == 17) vwait(13);
        else if (t == 18) vwait(15);
        else if (t <= 24) vwait(17);
        else if (t == 25) vwait(16);
        else if (t == 26) vwait(15);
        else if (t <= 29) vwait(14);
        else if (t == 30) vwait(10);
        else              vwait(6);

        const bf16_t* Vb = Vring + (t % 3) * 16384;
        bf16x8 Af[2], Bf[4];
        const int ch = ((t & 15) * 4 + quad) ^ (l16 & 7);
        #pragma unroll
        for (int m = 0; m < 2; ++m)
            Af[m] = *(const bf16x8*)&Pl[(m * 16 + l16) * 512 + ch * 8];
        #pragma unroll
        for (int n = 0; n < 4; ++n) {
            const int row = w * 64 + n * 16 + l16;
            Bf[n] = *(const bf16x8*)&Vb[row * 32 + ((quad ^ rsw) * 8)];
        }
        __builtin_amdgcn_s_setprio(1);
        if (t < 16) {
            #pragma unroll
            for (int n = 0; n < 4; ++n) {
                accA[0][n] = MFMA16(Af[0], Bf[n], accA[0][n]);
                accA[1][n] = MFMA16(Af[1], Bf[n], accA[1][n]);
            }
        } else {
            #pragma unroll
            for (int n = 0; n < 4; ++n) {
                accB[0][n] = MFMA16(Af[0], Bf[n], accB[0][n]);
                accB[1][n] = MFMA16(Af[1], Bf[n], accB[1][n]);
            }
        }
        __builtin_amdgcn_s_setprio(0);
        __builtin_amdgcn_sched_barrier(0);     // pin: MFMA | stage | stores
        if (t <= 28) stageV((t + 3) % 3, t + 3);
        __builtin_amdgcn_sched_barrier(0);
        if (t <= 23) zstore(48 + t * 2);       // rows 48..95
        if (t >= 16) {                         // accA scatter: 2 values/iter
            const int u = t - 16;
            #pragma unroll
            for (int vv = 0; vv < 2; ++vv) {
                const int v  = u * 2 + vv;     // 0..31
                const int m  = v >> 4, n = (v >> 2) & 3, rg = v & 3;
                const long tok = (long)s * SEG_W + off
                               + 4L * (band * 32 + m * 16 + quad * 4 + rg);
                const int d = w * 64 + n * 16 + l16;
                __builtin_nontemporal_store(accA[m][n][rg],
                                            obase + tok * D_MODEL + d);
            }
        }
    }

    // ================= epilogue: accB scatter only ========================
    #pragma unroll
    for (int m = 0; m < 2; ++m)
        #pragma unroll
        for (int rg = 0; rg < 4; ++rg) {
            const long tok = (long)s * SEG_W + off + 4L * (band * 32 + m * 16 + quad * 4 + rg);
            float* orow = obase + tok * D_MODEL;
            #pragma unroll
            for (int n = 0; n < 4; ++n) {
                const int d = w * 64 + n * 16 + l16;
                __builtin_nontemporal_store(accB[m][n][rg], orow + 512 + d);
            }
        }
}

extern "C" void kernel_launch(void* const* d_in, const int* in_sizes, int n_in,
                              void* d_out, int out_size, void* d_ws, size_t ws_size,
                              hipStream_t stream) {
    const float* x   = (const float*)d_in[0];
    const int*   hid = (const int*)d_in[1];
    float*       out = (float*)d_out;
    bf16_t* xg  = (bf16_t*)d_ws;
    bf16_t* xgT = xg + XG_ELEMS;      // ws: 33.6 MB

    gather_kernel<<<dim3(2048), dim3(256), 0, stream>>>(x, hid, xg, xgT);
    attn_kernel<<<dim3(256), dim3(512), 0, stream>>>(xg, xgT, hid, out);
}